// Round 1
// baseline (349.409 us; speedup 1.0000x reference)
//
#include <hip/hip_runtime.h>
#include <math.h>

#define BATCH 8
#define H 480
#define W 640
#define HW (H * W)
#define NPIX ((size_t)BATCH * HW)
#define PROP_TIME 16

// Fuse pass: per-pixel softmax over 9 guided channels, fold in the sparse
// mask:  w'_k = (1-mask) * softmax_k,  bias = mask * x0.
__global__ __launch_bounds__(256) void fuse_kernel(
    const float* __restrict__ guided,   // (B,9,H,W)
    const float* __restrict__ x,        // (B,1,H,W)
    const float* __restrict__ sparse,   // (B,1,H,W)
    float* __restrict__ wgt,            // (B,9,H,W) fused weights
    float* __restrict__ bias)           // (B,H,W)
{
    const int wc = blockIdx.x * 64 + threadIdx.x;   // column
    const int h  = blockIdx.y * 4  + threadIdx.y;   // row
    const int b  = blockIdx.z;
    const size_t phw = (size_t)h * W + wc;
    const size_t p   = (size_t)b * HW + phw;
    const size_t gbase = (size_t)b * 9 * HW + phw;

    float g[9];
    float m = -INFINITY;
#pragma unroll
    for (int k = 0; k < 9; ++k) {
        g[k] = guided[gbase + (size_t)k * HW];
        m = fmaxf(m, g[k]);
    }
    float s = 0.0f;
#pragma unroll
    for (int k = 0; k < 9; ++k) {
        g[k] = __expf(g[k] - m);
        s += g[k];
    }
    const float sv = sparse[p];
    const float mask = (sv > 0.0f) ? 1.0f : ((sv < 0.0f) ? -1.0f : 0.0f);
    const float scale = (1.0f - mask) / s;
#pragma unroll
    for (int k = 0; k < 9; ++k) {
        wgt[gbase + (size_t)k * HW] = g[k] * scale;
    }
    bias[p] = mask * x[p];
}

// One propagation step: xout = bias + sum_k w'_k * shift_k(xin)
__global__ __launch_bounds__(256) void prop_kernel(
    const float* __restrict__ xin,      // (B,H,W)
    const float* __restrict__ wgt,      // (B,9,H,W)
    const float* __restrict__ bias,     // (B,H,W)
    float* __restrict__ xout)           // (B,H,W)
{
    const int wc = blockIdx.x * 64 + threadIdx.x;
    const int h  = blockIdx.y * 4  + threadIdx.y;
    const int b  = blockIdx.z;
    const size_t phw = (size_t)h * W + wc;
    const size_t p   = (size_t)b * HW + phw;
    const float* __restrict__ xb = xin + (size_t)b * HW;
    const size_t wbase = (size_t)b * 9 * HW + phw;

    float acc = bias[p];
#pragma unroll
    for (int ki = 0; ki < 3; ++ki) {
        const int hh = h + ki - 1;
        const bool hok = (hh >= 0) && (hh < H);
#pragma unroll
        for (int kj = 0; kj < 3; ++kj) {
            const int ww = wc + kj - 1;
            const bool ok = hok && (ww >= 0) && (ww < W);
            const float v = ok ? xb[(size_t)hh * W + ww] : 0.0f;
            const float wk = wgt[wbase + (size_t)(ki * 3 + kj) * HW];
            acc = fmaf(wk, v, acc);
        }
    }
    xout[p] = acc;
}

extern "C" void kernel_launch(void* const* d_in, const int* in_sizes, int n_in,
                              void* d_out, int out_size, void* d_ws, size_t ws_size,
                              hipStream_t stream) {
    const float* guided = (const float*)d_in[0];
    const float* x      = (const float*)d_in[1];
    const float* sparse = (const float*)d_in[2];
    float* out = (float*)d_out;

    // workspace layout: wgt[9*N] | bias[N] | bufA[N] | bufB[N]  (12*N floats)
    float* wgt  = (float*)d_ws;
    float* bias = wgt + 9 * NPIX;
    float* bufA = bias + NPIX;
    float* bufB = bufA + NPIX;

    dim3 blk(64, 4, 1);
    dim3 grd(W / 64, H / 4, BATCH);   // 10 x 120 x 8, exact tiling

    fuse_kernel<<<grd, blk, 0, stream>>>(guided, x, sparse, wgt, bias);

    const float* cur = x;
    for (int t = 0; t < PROP_TIME; ++t) {
        float* dst = (t == PROP_TIME - 1) ? out : ((t & 1) ? bufB : bufA);
        prop_kernel<<<grd, blk, 0, stream>>>(cur, wgt, bias, dst);
        cur = dst;
    }
}

// Round 2
// 149.935 us; speedup vs baseline: 2.3304x; 2.3304x over previous
//
#include <hip/hip_runtime.h>
#include <hip/hip_fp16.h>
#include <math.h>

#define BATCH 8
#define H 480
#define W 640
#define HW (H * W)
#define NPIX ((size_t)BATCH * HW)

#define S 4            // steps fused per launch (16 total = 4 launches)
#define TX 64          // output tile width
#define TY 24          // output tile height
#define RX (TX + 2 * S)   // 72 region width
#define RY (TY + 2 * S)   // 32 region height
#define RN (RX * RY)      // 2304 region pixels
#define PXT (RN / 256)    // 9 pixels per thread

__device__ __forceinline__ float2 up2(unsigned u) {
    __half2 h = *reinterpret_cast<const __half2*>(&u);
    return __half22float2(h);
}

__device__ __forceinline__ unsigned pk2(float a, float b) {
    unsigned lo = __half_as_ushort(__float2half_rn(a));
    unsigned hi = __half_as_ushort(__float2half_rn(b));
    return lo | (hi << 16);
}

// Softmax + mask fold, packed fp16 output:
//   wpack[p] = {w0..w7} (uint4 of 8 halves), w9b[p] = {w8, bias} (half2)
//   where w_k = (1-mask)*softmax_k, bias = mask*x0.
__global__ __launch_bounds__(256) void fuse_kernel(
    const float* __restrict__ guided,   // (B,9,H,W)
    const float* __restrict__ x,        // (B,1,H,W)
    const float* __restrict__ sparse,   // (B,1,H,W)
    uint4* __restrict__ wpack,          // (B*HW) x 8 fp16
    unsigned* __restrict__ w9b)         // (B*HW) x {w8,bias} fp16
{
    const int wc = blockIdx.x * 64 + threadIdx.x;
    const int h  = blockIdx.y * 4  + threadIdx.y;
    const int b  = blockIdx.z;
    const size_t phw = (size_t)h * W + wc;
    const size_t p   = (size_t)b * HW + phw;
    const size_t gbase = (size_t)b * 9 * HW + phw;

    float g[9];
    float m = -INFINITY;
#pragma unroll
    for (int k = 0; k < 9; ++k) {
        g[k] = guided[gbase + (size_t)k * HW];
        m = fmaxf(m, g[k]);
    }
    float s = 0.0f;
#pragma unroll
    for (int k = 0; k < 9; ++k) {
        g[k] = __expf(g[k] - m);
        s += g[k];
    }
    const float sv = sparse[p];
    const float mask = (sv > 0.0f) ? 1.0f : ((sv < 0.0f) ? -1.0f : 0.0f);
    const float scale = (1.0f - mask) / s;

    uint4 wp;
    wp.x = pk2(g[0] * scale, g[1] * scale);
    wp.y = pk2(g[2] * scale, g[3] * scale);
    wp.z = pk2(g[4] * scale, g[5] * scale);
    wp.w = pk2(g[6] * scale, g[7] * scale);
    wpack[p] = wp;
    w9b[p] = pk2(g[8] * scale, mask * x[p]);
}

// Four fused propagation steps over a 72x32 region -> 64x24 output tile.
// Region x lives in LDS (single buffer, read/barrier/write/barrier per step);
// each thread keeps its 9 region-pixels' packed weights in registers.
__global__ __launch_bounds__(256) void prop4_kernel(
    const float* __restrict__ xin,      // (B,H,W)
    const uint4* __restrict__ wpack,
    const unsigned* __restrict__ w9b,
    float* __restrict__ xout)           // (B,H,W)
{
    __shared__ float xs[RN];

    const int tid = threadIdx.x;
    const int bx0 = blockIdx.x * TX;
    const int by0 = blockIdx.y * TY;
    const int b   = blockIdx.z;
    const size_t ob = (size_t)b * HW;
    const float* __restrict__ xb = xin + ob;

    uint4    wreg[PXT];
    unsigned wbr[PXT];

    // Load region x into LDS and weights into registers; zeros outside image.
#pragma unroll
    for (int k = 0; k < PXT; ++k) {
        const int idx = k * 256 + tid;
        const int r = idx / RX, c = idx % RX;
        const int gy = by0 - S + r;
        const int gx = bx0 - S + c;
        const bool ok = (gy >= 0) && (gy < H) && (gx >= 0) && (gx < W);
        if (ok) {
            const size_t q = (size_t)gy * W + gx;
            xs[idx] = xb[q];
            wreg[k] = wpack[ob + q];
            wbr[k]  = w9b[ob + q];
        } else {
            xs[idx] = 0.0f;
            wreg[k] = make_uint4(0u, 0u, 0u, 0u);
            wbr[k]  = 0u;
        }
    }
    __syncthreads();

#pragma unroll
    for (int t = 1; t <= S; ++t) {
        float acc[PXT];
#pragma unroll
        for (int k = 0; k < PXT; ++k) {
            const int idx = k * 256 + tid;
            const int r = idx / RX, c = idx % RX;
            const bool upd = (r >= t) && (r < RY - t) && (c >= t) && (c < RX - t);
            if (upd) {
                const float2 w01 = up2(wreg[k].x);
                const float2 w23 = up2(wreg[k].y);
                const float2 w45 = up2(wreg[k].z);
                const float2 w67 = up2(wreg[k].w);
                const float2 w8b = up2(wbr[k]);
                float a = w8b.y;                       // bias
                a = fmaf(w01.x, xs[idx - RX - 1], a);
                a = fmaf(w01.y, xs[idx - RX    ], a);
                a = fmaf(w23.x, xs[idx - RX + 1], a);
                a = fmaf(w23.y, xs[idx - 1     ], a);
                a = fmaf(w45.x, xs[idx         ], a);
                a = fmaf(w45.y, xs[idx + 1     ], a);
                a = fmaf(w67.x, xs[idx + RX - 1], a);
                a = fmaf(w67.y, xs[idx + RX    ], a);
                a = fmaf(w8b.x, xs[idx + RX + 1], a);
                acc[k] = a;
            }
        }
        __syncthreads();
#pragma unroll
        for (int k = 0; k < PXT; ++k) {
            const int idx = k * 256 + tid;
            const int r = idx / RX, c = idx % RX;
            const bool upd = (r >= t) && (r < RY - t) && (c >= t) && (c < RX - t);
            if (upd) xs[idx] = acc[k];
        }
        __syncthreads();
    }

    // Coalesced write-out of the 64x24 tile.
#pragma unroll
    for (int i = 0; i < (TX * TY) / 256; ++i) {
        const int j = i * 256 + tid;
        const int r = j / TX, c = j % TX;
        xout[ob + (size_t)(by0 + r) * W + (bx0 + c)] = xs[(r + S) * RX + (c + S)];
    }
}

extern "C" void kernel_launch(void* const* d_in, const int* in_sizes, int n_in,
                              void* d_out, int out_size, void* d_ws, size_t ws_size,
                              hipStream_t stream) {
    const float* guided = (const float*)d_in[0];
    const float* x      = (const float*)d_in[1];
    const float* sparse = (const float*)d_in[2];
    float* out = (float*)d_out;

    // ws layout: wpack (16B/px) | w9b (4B/px) | xA (4B/px) | xB (4B/px)
    uint4*    wpack = (uint4*)d_ws;
    unsigned* w9b   = (unsigned*)(wpack + NPIX);
    float*    xA    = (float*)(w9b + NPIX);
    float*    xB    = xA + NPIX;

    {
        dim3 blk(64, 4, 1);
        dim3 grd(W / 64, H / 4, BATCH);
        fuse_kernel<<<grd, blk, 0, stream>>>(guided, x, sparse, wpack, w9b);
    }

    dim3 blk(256, 1, 1);
    dim3 grd(W / TX, H / TY, BATCH);   // 10 x 20 x 8
    prop4_kernel<<<grd, blk, 0, stream>>>(x,  wpack, w9b, xA);
    prop4_kernel<<<grd, blk, 0, stream>>>(xA, wpack, w9b, xB);
    prop4_kernel<<<grd, blk, 0, stream>>>(xB, wpack, w9b, xA);
    prop4_kernel<<<grd, blk, 0, stream>>>(xA, wpack, w9b, out);
}